// Round 1
// baseline (1284.577 us; speedup 1.0000x reference)
//
#include <hip/hip_runtime.h>
#include <math.h>

#define NPTS   500000
#define BROWS  256
#define DIMS   128
#define TILE_N 64
#define INV_T  (1.0f / 0.07f)

typedef _Float16 half8  __attribute__((ext_vector_type(8)));
typedef float    floatx4 __attribute__((ext_vector_type(4)));

// Kernel 1: L2-normalize the 256 point rows -> f16 A in workspace; zero denom.
__global__ __launch_bounds__(64) void prep_kernel(const float* __restrict__ pts,
                                                  _Float16* __restrict__ A,
                                                  float* __restrict__ denom) {
    const int b = blockIdx.x;   // one row per block
    const int t = threadIdx.x;  // 64 threads = 1 wave
    float x0 = pts[b * DIMS + t];
    float x1 = pts[b * DIMS + 64 + t];
    float ss = x0 * x0 + x1 * x1;
#pragma unroll
    for (int off = 32; off > 0; off >>= 1) ss += __shfl_xor(ss, off, 64);
    float inv = 1.0f / sqrtf(ss);  // reference has no eps
    A[b * DIMS + t]      = (_Float16)(x0 * inv);
    A[b * DIMS + 64 + t] = (_Float16)(x1 * inv);
    if (t == 0) denom[b] = 0.0f;  // ws is re-poisoned each launch
}

// Kernel 2: S = A (256x128) * bank^T (128xN), fused per-row sum(exp(s/T)).
// Block tile: 256 rows x 64 cols. 4 waves; wave w owns rows [64w, 64w+64).
__global__ __launch_bounds__(256) void gemm_kernel(const float* __restrict__ bank,
                                                   const _Float16* __restrict__ A,
                                                   float* __restrict__ out,
                                                   float* __restrict__ denom) {
    __shared__ _Float16 Bs[TILE_N][DIMS + 8];  // +8 halfs pad: 2-way banks only (free)
    const int  tid = threadIdx.x;
    const long n0  = (long)blockIdx.x * TILE_N;

    // Stage bank tile (64 rows x 128 f32 = 32 KB) -> f16 LDS, coalesced float4.
    {
        const float* src = bank + n0 * DIMS;
#pragma unroll
        for (int i = 0; i < 8; i++) {
            int f   = (i * 256 + tid) * 4;  // flat f32 index in tile
            int row = f >> 7;
            int col = f & 127;
            float4 v = make_float4(0.f, 0.f, 0.f, 0.f);
            if (n0 + row < NPTS) v = *(const float4*)(src + f);
            _Float16* dst = &Bs[row][col];
            dst[0] = (_Float16)v.x;
            dst[1] = (_Float16)v.y;
            dst[2] = (_Float16)v.z;
            dst[3] = (_Float16)v.w;
        }
    }
    __syncthreads();

    const int w = tid >> 6;
    const int l = tid & 63;
    const int q = l >> 4;   // quad
    const int c = l & 15;
    const int mbase = w * 64;

    // A fragments from global workspace (64 KB, L2/L3-hot). A[m=lane&15][k=q*8+j].
    half8 a[4][4];
#pragma unroll
    for (int mt = 0; mt < 4; mt++)
#pragma unroll
        for (int ks = 0; ks < 4; ks++)
            a[mt][ks] = *(const half8*)(A + (mbase + mt * 16 + c) * DIMS + ks * 32 + q * 8);

    floatx4 acc[4][4];
#pragma unroll
    for (int mt = 0; mt < 4; mt++)
#pragma unroll
        for (int nt = 0; nt < 4; nt++)
            acc[mt][nt] = (floatx4){0.f, 0.f, 0.f, 0.f};

#pragma unroll
    for (int ks = 0; ks < 4; ks++) {
        half8 bf[4];  // B[k][n=lane&15] = bank[n][k] -> 16B LDS reads
#pragma unroll
        for (int nt = 0; nt < 4; nt++)
            bf[nt] = *(const half8*)(&Bs[nt * 16 + c][ks * 32 + q * 8]);
#pragma unroll
        for (int mt = 0; mt < 4; mt++)
#pragma unroll
            for (int nt = 0; nt < 4; nt++)
                acc[mt][nt] = __builtin_amdgcn_mfma_f32_16x16x32_f16(a[mt][ks], bf[nt],
                                                                     acc[mt][nt], 0, 0, 0);
    }

    // Epilogue: C/D layout col=lane&15, row=q*4+reg. Write S, accumulate exp sums.
    float* S = out + 1;  // out[0] is the loss
#pragma unroll
    for (int mt = 0; mt < 4; mt++) {
#pragma unroll
        for (int r = 0; r < 4; r++) {
            const int m = mbase + mt * 16 + q * 4 + r;
            float psum = 0.0f;
#pragma unroll
            for (int nt = 0; nt < 4; nt++) {
                long n = n0 + nt * 16 + c;
                if (n < NPTS) {
                    float s = acc[mt][nt][r];
                    S[(long)m * NPTS + n] = s;
                    psum += __expf(s * INV_T);  // <= exp(78.6) ~ 1.3e34, fits f32
                }
            }
            // reduce across the 16 lanes of this quad (they hold this row's cols)
#pragma unroll
            for (int off = 1; off < 16; off <<= 1) psum += __shfl_xor(psum, off, 64);
            if (c == 0) atomicAdd(&denom[m], psum);
        }
    }
}

// Kernel 3: loss = -mean(log(exp(S[b,idx[b]]/T)/denom[b] + 1e-7))
__global__ __launch_bounds__(256) void loss_kernel(const float* __restrict__ out_in,
                                                   const int* __restrict__ idx,
                                                   const float* __restrict__ denom,
                                                   float* __restrict__ out) {
    const int t = threadIdx.x;  // 256 threads, one per row
    const float* S = out_in + 1;
    long id = (long)idx[t];
    float s   = S[(long)t * NPTS + id];
    float pos = __expf(s * INV_T);
    float x   = pos / denom[t] + 1e-7f;
    float lg  = logf(x);
#pragma unroll
    for (int off = 32; off > 0; off >>= 1) lg += __shfl_xor(lg, off, 64);
    __shared__ float red[4];
    if ((t & 63) == 0) red[t >> 6] = lg;
    __syncthreads();
    if (t == 0) out[0] = -(red[0] + red[1] + red[2] + red[3]) * (1.0f / 256.0f);
}

extern "C" void kernel_launch(void* const* d_in, const int* in_sizes, int n_in,
                              void* d_out, int out_size, void* d_ws, size_t ws_size,
                              hipStream_t stream) {
    const float* points        = (const float*)d_in[0];
    const int*   point_indices = (const int*)d_in[1];
    const float* bank          = (const float*)d_in[2];
    float* out = (float*)d_out;

    _Float16* A     = (_Float16*)d_ws;                                      // 64 KB
    float*    denom = (float*)((char*)d_ws + BROWS * DIMS * sizeof(_Float16));  // 1 KB

    prep_kernel<<<BROWS, 64, 0, stream>>>(points, A, denom);
    const int nblocks = (NPTS + TILE_N - 1) / TILE_N;  // 7813
    gemm_kernel<<<nblocks, 256, 0, stream>>>(bank, A, out, denom);
    loss_kernel<<<1, 256, 0, stream>>>(out, point_indices, denom, out);
}

// Round 2
// 803.726 us; speedup vs baseline: 1.5983x; 1.5983x over previous
//
#include <hip/hip_runtime.h>
#include <math.h>

#define NPTS   500000
#define BROWS  256
#define DIMS   128
#define TILE_N 64
#define NTILES ((NPTS + TILE_N - 1) / TILE_N)  // 7813
#define NBLK   1024                            // persistent gemm blocks
#define INV_T  (1.0f / 0.07f)

typedef _Float16 half8  __attribute__((ext_vector_type(8)));
typedef float    floatx4 __attribute__((ext_vector_type(4)));

// Kernel 1: L2-normalize the 256 point rows -> f16 A in workspace.
__global__ __launch_bounds__(64) void prep_kernel(const float* __restrict__ pts,
                                                  _Float16* __restrict__ A) {
    const int b = blockIdx.x;   // one row per block
    const int t = threadIdx.x;  // 64 threads = 1 wave
    float x0 = pts[b * DIMS + t];
    float x1 = pts[b * DIMS + 64 + t];
    float ss = x0 * x0 + x1 * x1;
#pragma unroll
    for (int off = 32; off > 0; off >>= 1) ss += __shfl_xor(ss, off, 64);
    float inv = 1.0f / sqrtf(ss);  // reference has no eps
    A[b * DIMS + t]      = (_Float16)(x0 * inv);
    A[b * DIMS + 64 + t] = (_Float16)(x1 * inv);
}

// Kernel 2: S = A (256x128) * bank^T (128xN), fused per-row sum(exp(s/T)).
// Persistent blocks: grid-stride over N tiles; exp-sums accumulate in registers,
// ONE coalesced partial store per block at the end (no atomics).
__global__ __launch_bounds__(256) void gemm_kernel(const float* __restrict__ bank,
                                                   const _Float16* __restrict__ A,
                                                   float* __restrict__ out,
                                                   float* __restrict__ partial) {
    __shared__ _Float16 Bs[TILE_N][DIMS + 8];  // +8 halfs pad: 2-way banks only (free)
    __shared__ float    P[BROWS];
    const int tid = threadIdx.x;
    const int w = tid >> 6;
    const int l = tid & 63;
    const int q = l >> 4;   // quad
    const int c = l & 15;
    const int mbase = w * 64;   // wave w owns rows [64w, 64w+64)

    // A fragments once per block (64 KB workspace, L2/L3-hot). A[m=lane&15][k=q*8+j].
    half8 a[4][4];
#pragma unroll
    for (int mt = 0; mt < 4; mt++)
#pragma unroll
        for (int ks = 0; ks < 4; ks++)
            a[mt][ks] = *(const half8*)(A + (mbase + mt * 16 + c) * DIMS + ks * 32 + q * 8);

    float psum[4][4];  // [mt][r] running sum of exp over this block's columns
#pragma unroll
    for (int mt = 0; mt < 4; mt++)
#pragma unroll
        for (int r = 0; r < 4; r++) psum[mt][r] = 0.0f;

    float* S = out + 1;  // out[0] is the loss

    for (int tile = blockIdx.x; tile < NTILES; tile += NBLK) {
        const long n0 = (long)tile * TILE_N;

        // Stage bank tile (64 rows x 128 f32) -> f16 LDS, coalesced float4.
        {
            const float* src = bank + n0 * DIMS;
#pragma unroll
            for (int i = 0; i < 8; i++) {
                int f   = (i * 256 + tid) * 4;  // flat f32 index in tile
                int row = f >> 7;
                int col = f & 127;
                float4 v = make_float4(0.f, 0.f, 0.f, 0.f);
                if (n0 + row < NPTS) v = *(const float4*)(src + f);
                _Float16* dst = &Bs[row][col];
                dst[0] = (_Float16)v.x;
                dst[1] = (_Float16)v.y;
                dst[2] = (_Float16)v.z;
                dst[3] = (_Float16)v.w;
            }
        }
        __syncthreads();

        floatx4 acc[4][4];
#pragma unroll
        for (int mt = 0; mt < 4; mt++)
#pragma unroll
            for (int nt = 0; nt < 4; nt++)
                acc[mt][nt] = (floatx4){0.f, 0.f, 0.f, 0.f};

#pragma unroll
        for (int ks = 0; ks < 4; ks++) {
            half8 bf[4];  // B[k][n=lane&15] = bank[n][k] -> 16B LDS reads
#pragma unroll
            for (int nt = 0; nt < 4; nt++)
                bf[nt] = *(const half8*)(&Bs[nt * 16 + c][ks * 32 + q * 8]);
#pragma unroll
            for (int mt = 0; mt < 4; mt++)
#pragma unroll
                for (int nt = 0; nt < 4; nt++)
                    acc[mt][nt] = __builtin_amdgcn_mfma_f32_16x16x32_f16(a[mt][ks], bf[nt],
                                                                         acc[mt][nt], 0, 0, 0);
        }

        // Epilogue: C/D layout col=lane&15, row=q*4+reg. Write S, accumulate exps.
#pragma unroll
        for (int mt = 0; mt < 4; mt++) {
#pragma unroll
            for (int r = 0; r < 4; r++) {
                const int m = mbase + mt * 16 + q * 4 + r;
                float ps = 0.0f;
#pragma unroll
                for (int nt = 0; nt < 4; nt++) {
                    long n = n0 + nt * 16 + c;
                    if (n < NPTS) {
                        float s = acc[mt][nt][r];
                        S[(long)m * NPTS + n] = s;
                        ps += __expf(s * INV_T);  // <= exp(78.6) ~ 1.3e34, fits f32
                    }
                }
                psum[mt][r] += ps;
            }
        }
        __syncthreads();  // protect Bs before next tile's staging
    }

    // Block-level reduce: 16 quad lanes hold this row's column partials.
#pragma unroll
    for (int mt = 0; mt < 4; mt++) {
#pragma unroll
        for (int r = 0; r < 4; r++) {
            float v = psum[mt][r];
#pragma unroll
            for (int off = 1; off < 16; off <<= 1) v += __shfl_xor(v, off, 64);
            if (c == 0) P[mbase + mt * 16 + q * 4 + r] = v;
        }
    }
    __syncthreads();
    partial[(long)blockIdx.x * BROWS + tid] = P[tid];  // coalesced 1 KB store
}

// Kernel 3: denom[r] = sum over blocks of partial[b][r].
__global__ __launch_bounds__(256) void reduce_kernel(const float* __restrict__ partial,
                                                     float* __restrict__ denom) {
    const int r = blockIdx.x;
    const int t = threadIdx.x;
    float s = 0.0f;
    for (int b = t; b < NBLK; b += 256) s += partial[(long)b * BROWS + r];
#pragma unroll
    for (int off = 32; off > 0; off >>= 1) s += __shfl_xor(s, off, 64);
    __shared__ float red[4];
    if ((t & 63) == 0) red[t >> 6] = s;
    __syncthreads();
    if (t == 0) denom[r] = red[0] + red[1] + red[2] + red[3];
}

// Kernel 4: loss = -mean(log(exp(S[b,idx[b]]/T)/denom[b] + 1e-7))
__global__ __launch_bounds__(256) void loss_kernel(const float* __restrict__ out_in,
                                                   const int* __restrict__ idx,
                                                   const float* __restrict__ denom,
                                                   float* __restrict__ out) {
    const int t = threadIdx.x;  // 256 threads, one per row
    const float* S = out_in + 1;
    long id = (long)idx[t];
    float s   = S[(long)t * NPTS + id];
    float pos = __expf(s * INV_T);
    float x   = pos / denom[t] + 1e-7f;
    float lg  = logf(x);
#pragma unroll
    for (int off = 32; off > 0; off >>= 1) lg += __shfl_xor(lg, off, 64);
    __shared__ float red[4];
    if ((t & 63) == 0) red[t >> 6] = lg;
    __syncthreads();
    if (t == 0) out[0] = -(red[0] + red[1] + red[2] + red[3]) * (1.0f / 256.0f);
}

extern "C" void kernel_launch(void* const* d_in, const int* in_sizes, int n_in,
                              void* d_out, int out_size, void* d_ws, size_t ws_size,
                              hipStream_t stream) {
    const float* points        = (const float*)d_in[0];
    const int*   point_indices = (const int*)d_in[1];
    const float* bank          = (const float*)d_in[2];
    float* out = (float*)d_out;

    // ws layout: A (64 KB) | denom (1 KB) | partial (1 MB)
    _Float16* A       = (_Float16*)d_ws;
    float*    denom   = (float*)((char*)d_ws + 65536);
    float*    partial = (float*)((char*)d_ws + 65536 + 1024);

    prep_kernel<<<BROWS, 64, 0, stream>>>(points, A);
    gemm_kernel<<<NBLK, 256, 0, stream>>>(bank, A, out, partial);
    reduce_kernel<<<BROWS, 256, 0, stream>>>(partial, denom);
    loss_kernel<<<1, 256, 0, stream>>>(out, point_indices, denom, out);
}